// Round 6
// baseline (103.308 us; speedup 1.0000x reference)
//
#include <hip/hip_runtime.h>
#include <hip/hip_fp16.h>
#include <stdint.h>

#define N 512
#define NA 180
#define TD 64           // detectors per block
#define TI 64           // i-values per block
#define TW 100          // LDS tile pitch in pair-dwords (100%32=4: scrambled banks)
#define TH 94           // tile rows (span<=90 + margins)
#define TILE_DW (37 * 256)          // 9472 dw = 37888 B (data 9400) -> 4 blocks/CU
#define PP 708          // padded pair-image pitch (dwords)
#define PR 704          // padded pair-image rows
#define POFF 96         // padded index of image row/col 0

// d_ws float-offsets
#define WS_IMGPB  0
#define WS_IMGTPB (PR * PP)                 // 498432
#define WS_TAB    (2 * PR * PP)             // 996864 (16B aligned)
#define WS_FLAGS  (WS_TAB + 4 * NA)         // after 720 floats of tab
#define WS_OUTT   997888                    // 16B aligned; NA*512 floats

__device__ __forceinline__ void load16_to_lds(const uint32_t* g, uint32_t* l) {
    __builtin_amdgcn_global_load_lds(
        (const __attribute__((address_space(1))) void*)g,
        (__attribute__((address_space(3))) void*)l,
        16 /*bytes*/, 0 /*offset*/, 0 /*aux*/);
}

// Tiled pad: block (bx,by) covers a 64x64 padded region; builds BOTH the
// padded fp16-pair image (imgPB[r][c] = (h(I[r][c]), h(I[r][c+1]))) and its
// transpose, all reads/writes coalesced. Also: per-angle table + outT zeroing.
__global__ __launch_bounds__(256) void pad_kernel(const float* __restrict__ img,
                                                  const int* __restrict__ angles,
                                                  uint32_t* __restrict__ imgPB,
                                                  uint32_t* __restrict__ imgTPB,
                                                  float4* __restrict__ tab,
                                                  int* __restrict__ flags,
                                                  float* __restrict__ outT) {
    __shared__ float lds[65 * 66];   // pitch 66
    const int lane = threadIdx.x & 63;
    const int wq   = threadIdx.x >> 6;
    const int bx = blockIdx.x, by = blockIdx.y;
    const int b  = by * 11 + bx;

    if (b < 90) {                    // zero outT: 90*1024 floats = 92160
        float4 z; z.x = z.y = z.z = z.w = 0.0f;
        ((float4*)outT)[b * 256 + threadIdx.x] = z;
    }
    if (b == 120 && threadIdx.x < NA) {
        float t = (float)angles[threadIdx.x] * 0.017453292519943295f;
        float si = sinf(t), co = cosf(t);
        int useT = fabsf(si) > fabsf(co);
        float4 e;
        if (useT) { e.x = co; e.y = -si; e.z = si; e.w = co; }
        else      { e.x = si; e.y = co;  e.z = co; e.w = -si; }
        tab[threadIdx.x] = e;        // (au, bus, av, bvs)
        flags[threadIdx.x] = useT;
    }

    // stage 65x65 of the padded image: padded coords (by*64+r, bx*64+c)
    for (int idx = threadIdx.x; idx < 65 * 65; idx += 256) {
        int r = idx / 65, cc = idx - r * 65;
        int y = by * 64 + r - POFF, x = bx * 64 + cc - POFF;
        bool in = ((unsigned)y < N) && ((unsigned)x < N);
        lds[r * 66 + cc] = in ? img[y * N + x] : 0.0f;
    }
    __syncthreads();
#pragma unroll
    for (int j = 0; j < 16; ++j) {
        int r = wq * 16 + j;
        // imgPB[by*64+r][bx*64+lane] = (I[r][lane], I[r][lane+1])
        float v0 = lds[r * 66 + lane], v1 = lds[r * 66 + lane + 1];
        __half2 h = __halves2half2(__float2half(v0), __float2half(v1));
        imgPB[(size_t)(by * 64 + r) * PP + bx * 64 + lane] = *(uint32_t*)&h;
        // imgTPB[bx*64+r][by*64+lane] = (I[lane][r], I[lane+1][r])
        float t0 = lds[lane * 66 + r], t1 = lds[(lane + 1) * 66 + r];
        __half2 ht = __halves2half2(__float2half(t0), __float2half(t1));
        imgTPB[(size_t)(bx * 64 + r) * PP + by * 64 + lane] = *(uint32_t*)&ht;
    }
}

// One block = (1 angle, 64 detectors, 64 i). Footprint staged once into a
// 94x100 fp16-pair LDS tile (async 16B global->LDS); 1 ds_read2_b32 per
// bilinear sample; pk-f16 vertical lerp; merge + contiguous atomics to outT.
__global__ __launch_bounds__(256, 4) void radon_kernel(const uint32_t* __restrict__ imgPB,
                                                       const uint32_t* __restrict__ imgTPB,
                                                       const float4* __restrict__ tab,
                                                       const int* __restrict__ flags,
                                                       float* __restrict__ outT) {
    __shared__ uint32_t tile[TILE_DW];

    const int tid  = threadIdx.x;
    const int lane = tid & 63;
    const int wave = tid >> 6;
    const int d0 = blockIdx.x * TD;
    const int a  = blockIdx.y;
    const int i0 = blockIdx.z * TI;

    const float c = 255.5f;
    const float4 tb = tab[a];
    const float au = tb.x, bus = tb.y, av = tb.z, bvs = tb.w;

    // Monotone bbox: au, av have fixed sign per angle; fma is monotone per
    // operand, so extremes are at corner fi and extreme addend.
    const float fi0 = (float)i0 - c, fi1 = (float)(i0 + TI - 1) - c;
    const float xc0 = (float)d0 - c, xc1 = (float)(d0 + TD - 1) - c;
    const float buA = fmaf(bus, xc0, c), buB = fmaf(bus, xc1, c);
    const float bvA = fmaf(bvs, xc0, c), bvB = fmaf(bvs, xc1, c);
    const float buMin = fminf(buA, buB), buMax = fmaxf(buA, buB);
    const float bvMin = fminf(bvA, bvB), bvMax = fmaxf(bvA, bvB);
    const float fiLoU = (au >= 0.0f) ? fi0 : fi1, fiHiU = (au >= 0.0f) ? fi1 : fi0;
    const float fiLoV = (av >= 0.0f) ? fi0 : fi1, fiHiV = (av >= 0.0f) ? fi1 : fi0;
    const float umin = fmaf(au, fiLoU, buMin), umax = fmaf(au, fiHiU, buMax);
    const float vmin = fmaf(av, fiLoV, bvMin), vmax = fmaf(av, fiHiV, bvMax);

    // Entire block samples only zeros -> outT pre-zeroed, nothing to do.
    if (umin > (float)N || umax < -1.0f || vmin > (float)N || vmax < -1.0f) return;

    const int ub0 = (((int)floorf(umin)) & ~3) - 4;  // 16B-aligned, -4 col margin
    const int vb  = ((int)floorf(vmin)) - 1;         // -1 row margin

    const uint32_t* __restrict__ src = flags[a] ? imgTPB : imgPB;
    const uint32_t* gbase = src + (vb + POFF) * PP + (ub0 + POFF);

    // ---- stage 94x100 pair tile via async global->LDS, 16B per lane ----
#pragma unroll
    for (int s = 0; s < 10; ++s) {
        int chunk = s * 4 + wave;            // 0..39, need 0..36
        if (chunk < 37) {
            int tt = chunk * 256 + (lane << 2);
            int r  = tt / TW;
            int cc = tt - r * TW;
            load16_to_lds(gbase + r * PP + cc, &tile[chunk * 256]);
        }
    }
    __syncthreads();

    // ---- sample: lanes = 64 consecutive detectors, 16 i per wave ----
    const float xcl = (float)(d0 + lane) - c;
    const float bu_l2 = fmaf(bus, xcl, c) - (float)ub0;  // tile-local fold
    const float bv_l2 = fmaf(bvs, xcl, c) - (float)vb;

    float s1 = 0.0f, s2 = 0.0f;
    float fi = (float)(i0 + wave * 16) - c;
#pragma unroll
    for (int k = 0; k < 16; ++k) {
        float u = fmaf(au, fi, bu_l2);       // tile-local coords
        float v = fmaf(av, fi, bv_l2);
        fi += 1.0f;                          // exact (half-integers)
        float x0 = floorf(u), y0 = floorf(v);
        float wx = u - x0, wy = v - y0;
        float af = fmaf(y0, (float)TW, x0);  // exact int in f32
        int ai = (int)af;
        uint32_t P0 = tile[ai];
        uint32_t P1 = tile[ai + TW];         // merged -> ds_read2_b32 0/100
        __half2 p0h = *(__half2*)&P0;
        __half2 p1h = *(__half2*)&P1;
        __half2 dv  = __hsub2(p1h, p0h);
        __half2 wy2 = __float2half2_rn(wy);
        __half2 m   = __hfma2(wy2, dv, p0h); // (left, right) column lerps
        float lf = __low2float(m), hf = __high2float(m);
        s2 = fmaf(wx, hf - lf, s2);
        s1 += lf;
    }

    // ---- merge 4 wave-partials; contiguous-lane atomics into outT[a][d] ----
    __syncthreads();
    float* ft = (float*)tile;
    ft[tid] = s1 + s2;
    __syncthreads();
    if (tid < 64) {
        float r = ft[tid] + ft[tid + 64] + ft[tid + 128] + ft[tid + 192];
        atomicAdd(&outT[a * 512 + d0 + tid], r);
    }
}

// outT[a][d] -> out[d][a], fully overwriting out (no memset needed).
__global__ __launch_bounds__(256) void txo_kernel(const float* __restrict__ outT,
                                                  float* __restrict__ out) {
    __shared__ float lds[64 * 65];
    const int lane = threadIdx.x & 63;
    const int wq   = threadIdx.x >> 6;
    const int d0 = blockIdx.x * 64;
    const int a0 = blockIdx.y * 64;
#pragma unroll
    for (int j = 0; j < 16; ++j) {
        int r = wq * 16 + j;                 // angle row
        int a = a0 + r;
        lds[r * 65 + lane] = (a < NA) ? outT[a * 512 + d0 + lane] : 0.0f;
    }
    __syncthreads();
#pragma unroll
    for (int j = 0; j < 16; ++j) {
        int r = wq * 16 + j;                 // detector row
        int aa = a0 + lane;
        if (aa < NA) out[(d0 + r) * NA + aa] = lds[lane * 65 + r];
    }
}

extern "C" void kernel_launch(void* const* d_in, const int* in_sizes, int n_in,
                              void* d_out, int out_size, void* d_ws, size_t ws_size,
                              hipStream_t stream) {
    const float* img  = (const float*)d_in[0];
    const int* angles = (const int*)d_in[1];
    float* out = (float*)d_out;
    float* ws  = (float*)d_ws;

    uint32_t* imgPB  = (uint32_t*)(ws + WS_IMGPB);
    uint32_t* imgTPB = (uint32_t*)(ws + WS_IMGTPB);
    float4*   tab    = (float4*)(ws + WS_TAB);
    int*      flags  = (int*)(ws + WS_FLAGS);
    float*    outT   = ws + WS_OUTT;

    dim3 pgrid(11, 11);
    pad_kernel<<<pgrid, 256, 0, stream>>>(img, angles, imgPB, imgTPB, tab, flags, outT);

    dim3 grid(N / TD, NA, N / TI);
    radon_kernel<<<grid, 256, 0, stream>>>(imgPB, imgTPB, tab, flags, outT);

    dim3 tgrid(512 / 64, 3);
    txo_kernel<<<tgrid, 256, 0, stream>>>(outT, out);
}

// Round 8
// 100.617 us; speedup vs baseline: 1.0267x; 1.0267x over previous
//
#include <hip/hip_runtime.h>
#include <hip/hip_fp16.h>
#include <stdint.h>

#define N 512
#define NA 180
#define TD 64           // detectors per block
#define TI 64           // i-values per block
#define TW 96           // LDS tile pitch in pair-dwords
#define TILE_DW (36 * 256)          // 9216 dw = 36864 B -> 4 blocks/CU @ 512 thr = 100% occ
#define PP 708          // padded pair-image pitch (dwords)
#define PR 704          // padded pair-image rows
#define POFF 96         // padded index of image row/col 0

// d_ws float-offsets
#define WS_IMGPB  0
#define WS_IMGTPB (PR * PP)                 // 498432
#define WS_TAB    (2 * PR * PP)             // 996864 (16B aligned)
#define WS_FLAGS  (WS_TAB + 4 * NA)
#define WS_OUTT   997888                    // 16B aligned; NA*512 floats

typedef _Float16 hh2 __attribute__((ext_vector_type(2)));
union H2U { uint32_t u; hh2 h; };

__device__ __forceinline__ hh2 cvt_pkrtz(float a, float b) {
    return __builtin_bit_cast(hh2, __builtin_amdgcn_cvt_pkrtz(a, b));
}

__device__ __forceinline__ void load16_to_lds(const uint32_t* g, uint32_t* l) {
    __builtin_amdgcn_global_load_lds(
        (const __attribute__((address_space(1))) void*)g,
        (__attribute__((address_space(3))) void*)l,
        16 /*bytes*/, 0 /*offset*/, 0 /*aux*/);
}

// Tiled pad: block (bx,by) covers a 64x64 padded region; builds BOTH the
// padded fp16-pair image (imgPB[r][c] = (h(I[r][c]), h(I[r][c+1]))) and its
// transpose, all reads/writes coalesced. Also: per-angle table + outT zeroing.
__global__ __launch_bounds__(256) void pad_kernel(const float* __restrict__ img,
                                                  const int* __restrict__ angles,
                                                  uint32_t* __restrict__ imgPB,
                                                  uint32_t* __restrict__ imgTPB,
                                                  float4* __restrict__ tab,
                                                  int* __restrict__ flags,
                                                  float* __restrict__ outT) {
    __shared__ float lds[65 * 66];   // pitch 66
    const int lane = threadIdx.x & 63;
    const int wq   = threadIdx.x >> 6;
    const int bx = blockIdx.x, by = blockIdx.y;
    const int b  = by * 11 + bx;

    if (b < 90) {                    // zero outT: 90*1024 floats = 92160
        float4 z; z.x = z.y = z.z = z.w = 0.0f;
        ((float4*)outT)[b * 256 + threadIdx.x] = z;
    }
    if (b == 120 && threadIdx.x < NA) {
        float t = (float)angles[threadIdx.x] * 0.017453292519943295f;
        float si = sinf(t), co = cosf(t);
        int useT = fabsf(si) > fabsf(co);
        float4 e;
        if (useT) { e.x = co; e.y = -si; e.z = si; e.w = co; }
        else      { e.x = si; e.y = co;  e.z = co; e.w = -si; }
        tab[threadIdx.x] = e;        // (au, bus, av, bvs)
        flags[threadIdx.x] = useT;
    }

    // stage 65x65 of the padded image: padded coords (by*64+r, bx*64+c)
    for (int idx = threadIdx.x; idx < 65 * 65; idx += 256) {
        int r = idx / 65, cc = idx - r * 65;
        int y = by * 64 + r - POFF, x = bx * 64 + cc - POFF;
        bool in = ((unsigned)y < N) && ((unsigned)x < N);
        lds[r * 66 + cc] = in ? img[y * N + x] : 0.0f;
    }
    __syncthreads();
#pragma unroll
    for (int j = 0; j < 16; ++j) {
        int r = wq * 16 + j;
        float v0 = lds[r * 66 + lane], v1 = lds[r * 66 + lane + 1];
        __half2 h = __halves2half2(__float2half(v0), __float2half(v1));
        imgPB[(size_t)(by * 64 + r) * PP + bx * 64 + lane] = *(uint32_t*)&h;
        float t0 = lds[lane * 66 + r], t1 = lds[(lane + 1) * 66 + r];
        __half2 ht = __halves2half2(__float2half(t0), __float2half(t1));
        imgTPB[(size_t)(bx * 64 + r) * PP + by * 64 + lane] = *(uint32_t*)&ht;
    }
}

// One block = (1 angle, 64 detectors, 64 i) with 512 threads (8 waves x 8 i).
// 36.9 KB tile x 4 blocks/CU x 512 thr = 2048 thr/CU -> 100% wave occupancy.
__global__ __launch_bounds__(512, 8) void radon_kernel(const uint32_t* __restrict__ imgPB,
                                                       const uint32_t* __restrict__ imgTPB,
                                                       const float4* __restrict__ tab,
                                                       const int* __restrict__ flags,
                                                       float* __restrict__ outT) {
    __shared__ uint32_t tile[TILE_DW];

    const int tid  = threadIdx.x;
    const int lane = tid & 63;
    const int wave = tid >> 6;           // 0..7
    const int d0 = blockIdx.x * TD;
    const int a  = blockIdx.y;
    const int i0 = blockIdx.z * TI;

    const float c = 255.5f;
    const float4 tb = tab[a];
    const float au = tb.x, bus = tb.y, av = tb.z, bvs = tb.w;

    // Monotone bbox (au, av have fixed sign; fma monotone per operand).
    const float fi0 = (float)i0 - c, fi1 = (float)(i0 + TI - 1) - c;
    const float xc0 = (float)d0 - c, xc1 = (float)(d0 + TD - 1) - c;
    const float buA = fmaf(bus, xc0, c), buB = fmaf(bus, xc1, c);
    const float bvA = fmaf(bvs, xc0, c), bvB = fmaf(bvs, xc1, c);
    const float buMin = fminf(buA, buB), buMax = fmaxf(buA, buB);
    const float bvMin = fminf(bvA, bvB), bvMax = fmaxf(bvA, bvB);
    const float fiLoU = (au >= 0.0f) ? fi0 : fi1, fiHiU = (au >= 0.0f) ? fi1 : fi0;
    const float fiLoV = (av >= 0.0f) ? fi0 : fi1, fiHiV = (av >= 0.0f) ? fi1 : fi0;
    const float umin = fmaf(au, fiLoU, buMin), umax = fmaf(au, fiHiU, buMax);
    const float vmin = fmaf(av, fiLoV, bvMin), vmax = fmaf(av, fiHiV, bvMax);

    // Entire block samples only zeros -> outT pre-zeroed, nothing to do.
    if (umin > (float)N || umax < -1.0f || vmin > (float)N || vmax < -1.0f) return;

    // >=1-texel left/top margin so ulp-level floor flips can never go negative.
    const int ub0 = (((int)floorf(umin)) - 1) & ~3;   // 16B-aligned
    const int vb  = ((int)floorf(vmin)) - 1;

    const uint32_t* __restrict__ src = flags[a] ? imgTPB : imgPB;
    const uint32_t* gbase = src + (vb + POFF) * PP + (ub0 + POFF);

    // ---- stage 96x96 pair tile (36 chunks of 1 KB), async global->LDS ----
#pragma unroll
    for (int s = 0; s < 5; ++s) {
        int chunk = s * 8 + wave;            // 0..39, need 0..35
        if (chunk < 36) {
            int tt = chunk * 256 + (lane << 2);
            int r  = tt / TW;
            int cc = tt - r * TW;
            load16_to_lds(gbase + r * PP + cc, &tile[chunk * 256]);
        }
    }
    __syncthreads();

    // ---- sample: lanes = 64 consecutive detectors, 8 i per wave ----
    const float xcl = (float)(d0 + lane) - c;
    const float buL = fmaf(bus, xcl, c) - (float)ub0;  // tile-local fold
    const float bvL = fmaf(bvs, xcl, c) - (float)vb;

    float s = 0.0f;
    float fi = (float)(i0 + wave * 8) - c;
#pragma unroll
    for (int k = 0; k < 8; ++k) {
        float u = fmaf(au, fi, buL);         // tile-local, > 0 by margin
        float v = fmaf(av, fi, bvL);
        fi += 1.0f;                          // exact (half-integers)
        float wx = __builtin_amdgcn_fractf(u);
        float wy = __builtin_amdgcn_fractf(v);
        int iu = (int)u, iv = (int)v;        // trunc == floor (positive)
        int ai = iv * TW + iu;
        H2U P0, P1;
        P0.u = tile[ai];
        P1.u = tile[ai + TW];                // merged -> ds_read2_b32 0/96
        hh2 wy2 = cvt_pkrtz(wy, wy);
        hh2 m   = wy2 * (P1.h - P0.h) + P0.h;          // pk f16 lerp (vertical)
        hh2 wv  = cvt_pkrtz(1.0f - wx, wx);
#if __has_builtin(__builtin_amdgcn_fdot2)
        s = __builtin_amdgcn_fdot2(wv, m, s, false);   // horiz lerp + accum
#else
        s += (1.0f - wx) * (float)m.x + wx * (float)m.y;
#endif
    }

    // ---- merge 8 wave-partials; contiguous-lane atomics into outT[a][d] ----
    __syncthreads();
    float* ft = (float*)tile;
    ft[tid] = s;
    __syncthreads();
    if (tid < 64) {
        float r = ft[tid]       + ft[tid + 64]  + ft[tid + 128] + ft[tid + 192]
                + ft[tid + 256] + ft[tid + 320] + ft[tid + 384] + ft[tid + 448];
        atomicAdd(&outT[a * 512 + d0 + tid], r);
    }
}

// outT[a][d] -> out[d][a], fully overwriting out (no memset needed).
__global__ __launch_bounds__(256) void txo_kernel(const float* __restrict__ outT,
                                                  float* __restrict__ out) {
    __shared__ float lds[64 * 65];
    const int lane = threadIdx.x & 63;
    const int wq   = threadIdx.x >> 6;
    const int d0 = blockIdx.x * 64;
    const int a0 = blockIdx.y * 64;
#pragma unroll
    for (int j = 0; j < 16; ++j) {
        int r = wq * 16 + j;                 // angle row
        int a = a0 + r;
        lds[r * 65 + lane] = (a < NA) ? outT[a * 512 + d0 + lane] : 0.0f;
    }
    __syncthreads();
#pragma unroll
    for (int j = 0; j < 16; ++j) {
        int r = wq * 16 + j;                 // detector row
        int aa = a0 + lane;
        if (aa < NA) out[(d0 + r) * NA + aa] = lds[lane * 65 + r];
    }
}

extern "C" void kernel_launch(void* const* d_in, const int* in_sizes, int n_in,
                              void* d_out, int out_size, void* d_ws, size_t ws_size,
                              hipStream_t stream) {
    const float* img  = (const float*)d_in[0];
    const int* angles = (const int*)d_in[1];
    float* out = (float*)d_out;
    float* ws  = (float*)d_ws;

    uint32_t* imgPB  = (uint32_t*)(ws + WS_IMGPB);
    uint32_t* imgTPB = (uint32_t*)(ws + WS_IMGTPB);
    float4*   tab    = (float4*)(ws + WS_TAB);
    int*      flags  = (int*)(ws + WS_FLAGS);
    float*    outT   = ws + WS_OUTT;

    dim3 pgrid(11, 11);
    pad_kernel<<<pgrid, 256, 0, stream>>>(img, angles, imgPB, imgTPB, tab, flags, outT);

    dim3 grid(N / TD, NA, N / TI);
    radon_kernel<<<grid, 512, 0, stream>>>(imgPB, imgTPB, tab, flags, outT);

    dim3 tgrid(512 / 64, 3);
    txo_kernel<<<tgrid, 256, 0, stream>>>(outT, out);
}

// Round 10
// 97.334 us; speedup vs baseline: 1.0614x; 1.0337x over previous
//
#include <hip/hip_runtime.h>
#include <hip/hip_fp16.h>
#include <stdint.h>

#define N 512
#define NA 180
#define TD 64           // detectors per block
#define TI 128          // i-values per block (2 phases of 64)
#define TW 96           // LDS tile pitch in pair-dwords
#define TILE_DW (36 * 256)          // 9216 dw = 36864 B -> 4 blocks/CU @ 512 thr
#define PP 708          // padded pair-image pitch (dwords)
#define PR 704          // padded pair-image rows
#define POFF 96         // padded index of image row/col 0

// d_ws float-offsets
#define WS_IMGPB  0
#define WS_IMGTPB (PR * PP)                 // 498432
#define WS_TAB    (2 * PR * PP)             // 996864 (16B aligned)
#define WS_FLAGS  (WS_TAB + 4 * NA)
#define WS_OUTT   997888                    // 16B aligned; NA*512 floats

typedef _Float16 hh2 __attribute__((ext_vector_type(2)));
union H2U { uint32_t u; hh2 h; };

__device__ __forceinline__ hh2 cvt_pkrtz(float a, float b) {
    return __builtin_bit_cast(hh2, __builtin_amdgcn_cvt_pkrtz(a, b));
}

__device__ __forceinline__ void load16_to_lds(const uint32_t* g, uint32_t* l) {
    __builtin_amdgcn_global_load_lds(
        (const __attribute__((address_space(1))) void*)g,
        (__attribute__((address_space(3))) void*)l,
        16 /*bytes*/, 0 /*offset*/, 0 /*aux*/);
}

// Tiled pad (512 thr): block (bx,by) covers a 64x64 padded region; builds the
// padded fp16-pair image (imgPB[r][c] = (h(I[r][c]), h(I[r][c+1]))) and its
// transpose, all accesses coalesced. Also per-angle table + outT zeroing.
__global__ __launch_bounds__(512) void pad_kernel(const float* __restrict__ img,
                                                  const int* __restrict__ angles,
                                                  uint32_t* __restrict__ imgPB,
                                                  uint32_t* __restrict__ imgTPB,
                                                  float4* __restrict__ tab,
                                                  int* __restrict__ flags,
                                                  float* __restrict__ outT) {
    __shared__ float lds[65 * 66];   // pitch 66
    const int tid  = threadIdx.x;
    const int lane = tid & 63;
    const int wq   = tid >> 6;       // 0..7
    const int bx = blockIdx.x, by = blockIdx.y;
    const int b  = by * 11 + bx;

    if (b < 45) {                    // zero outT: 45*512 float4 = 92160 floats
        float4 z; z.x = z.y = z.z = z.w = 0.0f;
        ((float4*)outT)[b * 512 + tid] = z;
    }
    if (b == 120 && tid < NA) {
        float t = (float)angles[tid] * 0.017453292519943295f;
        float si = sinf(t), co = cosf(t);
        int useT = fabsf(si) > fabsf(co);
        float4 e;
        if (useT) { e.x = co; e.y = -si; e.z = si; e.w = co; }
        else      { e.x = si; e.y = co;  e.z = co; e.w = -si; }
        tab[tid] = e;                // (au, bus, av, bvs)
        flags[tid] = useT;
    }

    // stage 65x65 of the padded image: padded coords (by*64+r, bx*64+c)
    for (int idx = tid; idx < 65 * 65; idx += 512) {
        int r = idx / 65, cc = idx - r * 65;
        int y = by * 64 + r - POFF, x = bx * 64 + cc - POFF;
        bool in = ((unsigned)y < N) && ((unsigned)x < N);
        lds[r * 66 + cc] = in ? img[y * N + x] : 0.0f;
    }
    __syncthreads();
#pragma unroll
    for (int j = 0; j < 8; ++j) {
        int r = wq * 8 + j;
        float v0 = lds[r * 66 + lane], v1 = lds[r * 66 + lane + 1];
        __half2 h = __halves2half2(__float2half(v0), __float2half(v1));
        imgPB[(size_t)(by * 64 + r) * PP + bx * 64 + lane] = *(uint32_t*)&h;
        float t0 = lds[lane * 66 + r], t1 = lds[(lane + 1) * 66 + r];
        __half2 ht = __halves2half2(__float2half(t0), __float2half(t1));
        imgTPB[(size_t)(bx * 64 + r) * PP + by * 64 + lane] = *(uint32_t*)&ht;
    }
}

// One block = (1 angle, 64 detectors, 128 i): two phases of (stage 96x96
// fp16-pair tile, sample 8 i/wave). 36.9 KB x 4 blocks/CU x 512 thr = 100%
// wave occupancy. Prologue/merge amortized over 2 phases.
__global__ __launch_bounds__(512, 8) void radon_kernel(const uint32_t* __restrict__ imgPB,
                                                       const uint32_t* __restrict__ imgTPB,
                                                       const float4* __restrict__ tab,
                                                       const int* __restrict__ flags,
                                                       float* __restrict__ outT) {
    __shared__ uint32_t tile[TILE_DW];

    const int tid  = threadIdx.x;
    const int lane = tid & 63;
    const int wave = tid >> 6;           // 0..7
    const int d0 = blockIdx.x * TD;
    const int a  = blockIdx.y;
    const int i0 = blockIdx.z * TI;

    const float c = 255.5f;
    const float4 tb = tab[a];
    const float au = tb.x, bus = tb.y, av = tb.z, bvs = tb.w;

    // d-extremes of the affine offset (fixed for the whole block)
    const float xc0 = (float)d0 - c, xc1 = (float)(d0 + TD - 1) - c;
    const float buA = fmaf(bus, xc0, c), buB = fmaf(bus, xc1, c);
    const float bvA = fmaf(bvs, xc0, c), bvB = fmaf(bvs, xc1, c);
    const float buMin = fminf(buA, buB), buMax = fmaxf(buA, buB);
    const float bvMin = fminf(bvA, bvB), bvMax = fmaxf(bvA, bvB);

    // whole-block bbox (fi over all 128 i): early out if nothing can hit
    {
        const float fi0 = (float)i0 - c, fi1 = (float)(i0 + TI - 1) - c;
        const float fiLoU = (au >= 0.0f) ? fi0 : fi1, fiHiU = (au >= 0.0f) ? fi1 : fi0;
        const float fiLoV = (av >= 0.0f) ? fi0 : fi1, fiHiV = (av >= 0.0f) ? fi1 : fi0;
        if (fmaf(au, fiLoU, buMin) > (float)N || fmaf(au, fiHiU, buMax) < -1.0f ||
            fmaf(av, fiLoV, bvMin) > (float)N || fmaf(av, fiHiV, bvMax) < -1.0f)
            return;
    }

    const uint32_t* __restrict__ src = flags[a] ? imgTPB : imgPB;

    // per-lane affine offsets (shared by both phases)
    const float xcl = (float)(d0 + lane) - c;
    const float buLb = fmaf(bus, xcl, c);
    const float bvLb = fmaf(bvs, xcl, c);

    // incremental staging address bases (per lane, shared by both phases)
    const int t0g  = wave * 256 + (lane << 2);   // dword index into tile
    const int q0   = t0g / TW;
    const int c0   = t0g - q0 * TW;
    const int goff0 = q0 * PP + c0;              // dword offset from gbase

    float s = 0.0f;
#pragma unroll
    for (int ph = 0; ph < 2; ++ph) {
        const int ip = i0 + ph * 64;
        const float fi0 = (float)ip - c, fi1 = (float)(ip + 63) - c;
        const float fiLoU = (au >= 0.0f) ? fi0 : fi1, fiHiU = (au >= 0.0f) ? fi1 : fi0;
        const float fiLoV = (av >= 0.0f) ? fi0 : fi1, fiHiV = (av >= 0.0f) ? fi1 : fi0;
        const float umin = fmaf(au, fiLoU, buMin), umax = fmaf(au, fiHiU, buMax);
        const float vmin = fmaf(av, fiLoV, bvMin), vmax = fmaf(av, fiHiV, bvMax);
        const bool live = !(umin > (float)N || umax < -1.0f ||
                            vmin > (float)N || vmax < -1.0f);

        // >=1-texel margins; for live phases umin >= -90.3 so cols/rows stay
        // inside the 96-apron (no OOB).
        const int ub0 = (((int)floorf(umin)) - 1) & ~3;
        const int vb  = ((int)floorf(vmin)) - 1;

        __syncthreads();                 // WAR: prev phase sampling complete
        if (live) {
            const uint32_t* gb = src + (vb + POFF) * PP + (ub0 + POFF) + goff0;
            int cc = c0;
#pragma unroll
            for (int st = 0; st < 5; ++st) {
                int chunk = st * 8 + wave;        // 0..39, need 0..35
                if (chunk < 36) load16_to_lds(gb, &tile[chunk * 256]);
                // advance by 2048 tile-dwords = 21 rows + 32 cols (mod 96)
                cc += 32;
                int wrap = (cc >= TW);
                cc = wrap ? cc - TW : cc;
                gb += 21 * PP + 32 + (wrap ? (PP - TW) : 0);   // fixed wrap
            }
        }
        __syncthreads();                 // RAW: staging visible
        if (live) {
            const float buL = buLb - (float)ub0;   // tile-local fold
            const float bvL = bvLb - (float)vb;
            const float fiw = (float)(ip + wave * 8) - c;
            float u = fmaf(au, fiw, buL);
            float v = fmaf(av, fiw, bvL);
#pragma unroll
            for (int k = 0; k < 8; ++k) {
                float wx = __builtin_amdgcn_fractf(u);
                float wy = __builtin_amdgcn_fractf(v);
                int iu = (int)u, iv = (int)v;      // trunc == floor (u,v > 0)
                int ai = iv * TW + iu;
                H2U P0, P1;
                P0.u = tile[ai];
                P1.u = tile[ai + TW];              // ds_read2_b32 0/96
                hh2 wy2 = cvt_pkrtz(wy, wy);
                hh2 m   = wy2 * (P1.h - P0.h) + P0.h;   // pk f16 vertical lerp
                hh2 wv  = cvt_pkrtz(1.0f - wx, wx);
                s = __builtin_amdgcn_fdot2(wv, m, s, false);
                u += au;                           // incremental (drift < 1e-4 px)
                v += av;
            }
        }
    }

    // ---- merge 8 wave-partials; contiguous-lane atomics into outT[a][d] ----
    __syncthreads();
    float* ft = (float*)tile;
    ft[tid] = s;
    __syncthreads();
    if (tid < 64) {
        float r = ft[tid]       + ft[tid + 64]  + ft[tid + 128] + ft[tid + 192]
                + ft[tid + 256] + ft[tid + 320] + ft[tid + 384] + ft[tid + 448];
        atomicAdd(&outT[a * 512 + d0 + tid], r);
    }
}

// outT[a][d] -> out[d][a], fully overwriting out (no memset needed).
__global__ __launch_bounds__(256) void txo_kernel(const float* __restrict__ outT,
                                                  float* __restrict__ out) {
    __shared__ float lds[64 * 65];
    const int lane = threadIdx.x & 63;
    const int wq   = threadIdx.x >> 6;
    const int d0 = blockIdx.x * 64;
    const int a0 = blockIdx.y * 64;
#pragma unroll
    for (int j = 0; j < 16; ++j) {
        int r = wq * 16 + j;                 // angle row
        int a = a0 + r;
        lds[r * 65 + lane] = (a < NA) ? outT[a * 512 + d0 + lane] : 0.0f;
    }
    __syncthreads();
#pragma unroll
    for (int j = 0; j < 16; ++j) {
        int r = wq * 16 + j;                 // detector row
        int aa = a0 + lane;
        if (aa < NA) out[(d0 + r) * NA + aa] = lds[lane * 65 + r];
    }
}

extern "C" void kernel_launch(void* const* d_in, const int* in_sizes, int n_in,
                              void* d_out, int out_size, void* d_ws, size_t ws_size,
                              hipStream_t stream) {
    const float* img  = (const float*)d_in[0];
    const int* angles = (const int*)d_in[1];
    float* out = (float*)d_out;
    float* ws  = (float*)d_ws;

    uint32_t* imgPB  = (uint32_t*)(ws + WS_IMGPB);
    uint32_t* imgTPB = (uint32_t*)(ws + WS_IMGTPB);
    float4*   tab    = (float4*)(ws + WS_TAB);
    int*      flags  = (int*)(ws + WS_FLAGS);
    float*    outT   = ws + WS_OUTT;

    dim3 pgrid(11, 11);
    pad_kernel<<<pgrid, 512, 0, stream>>>(img, angles, imgPB, imgTPB, tab, flags, outT);

    dim3 grid(N / TD, NA, N / TI);
    radon_kernel<<<grid, 512, 0, stream>>>(imgPB, imgTPB, tab, flags, outT);

    dim3 tgrid(512 / 64, 3);
    txo_kernel<<<tgrid, 256, 0, stream>>>(outT, out);
}

// Round 11
// 92.764 us; speedup vs baseline: 1.1137x; 1.0493x over previous
//
#include <hip/hip_runtime.h>
#include <hip/hip_fp16.h>
#include <stdint.h>

#define N 512
#define NA 180
#define TD 64           // detectors per block
#define TI 256          // i-values per block (4 phases of 64)
#define TW 96           // LDS tile pitch in pair-dwords
#define TILE_DW (36 * 256)          // 9216 dw = 36864 B -> 4 blocks/CU @ 512 thr
#define PP 708          // padded pair-image pitch (dwords)
#define PR 704          // padded pair-image rows
#define POFF 96         // padded index of image row/col 0

// d_ws float-offsets
#define WS_IMGPB  0
#define WS_IMGTPB (PR * PP)                 // 498432
#define WS_TAB    (2 * PR * PP)             // 996864 (16B aligned)
#define WS_FLAGS  (WS_TAB + 4 * NA)

typedef _Float16 hh2 __attribute__((ext_vector_type(2)));
union H2U { uint32_t u; hh2 h; };

__device__ __forceinline__ hh2 cvt_pkrtz(float a, float b) {
    return __builtin_bit_cast(hh2, __builtin_amdgcn_cvt_pkrtz(a, b));
}

__device__ __forceinline__ void load16_to_lds(const uint32_t* g, uint32_t* l) {
    __builtin_amdgcn_global_load_lds(
        (const __attribute__((address_space(1))) void*)g,
        (__attribute__((address_space(3))) void*)l,
        16 /*bytes*/, 0 /*offset*/, 0 /*aux*/);
}

// Tiled pad (512 thr): block (bx,by) covers a 64x64 padded region; builds the
// padded fp16-pair image (imgPB[r][c] = (h(I[r][c]), h(I[r][c+1]))) and its
// transpose, all accesses coalesced. Also per-angle table + zeroing `out`
// (radon accumulates into out directly; 512*180 floats = 45 blocks x 512 f4).
__global__ __launch_bounds__(512) void pad_kernel(const float* __restrict__ img,
                                                  const int* __restrict__ angles,
                                                  uint32_t* __restrict__ imgPB,
                                                  uint32_t* __restrict__ imgTPB,
                                                  float4* __restrict__ tab,
                                                  int* __restrict__ flags,
                                                  float* __restrict__ out) {
    __shared__ float lds[65 * 66];   // pitch 66
    const int tid  = threadIdx.x;
    const int lane = tid & 63;
    const int wq   = tid >> 6;       // 0..7
    const int bx = blockIdx.x, by = blockIdx.y;
    const int b  = by * 11 + bx;

    if (b < 45) {                    // zero out: 45*512 float4 = 92160 floats
        float4 z; z.x = z.y = z.z = z.w = 0.0f;
        ((float4*)out)[b * 512 + tid] = z;
    }
    if (b == 120 && tid < NA) {
        float t = (float)angles[tid] * 0.017453292519943295f;
        float si = sinf(t), co = cosf(t);
        int useT = fabsf(si) > fabsf(co);
        float4 e;
        if (useT) { e.x = co; e.y = -si; e.z = si; e.w = co; }
        else      { e.x = si; e.y = co;  e.z = co; e.w = -si; }
        tab[tid] = e;                // (au, bus, av, bvs)
        flags[tid] = useT;
    }

    // stage 65x65 of the padded image: padded coords (by*64+r, bx*64+c)
    for (int idx = tid; idx < 65 * 65; idx += 512) {
        int r = idx / 65, cc = idx - r * 65;
        int y = by * 64 + r - POFF, x = bx * 64 + cc - POFF;
        bool in = ((unsigned)y < N) && ((unsigned)x < N);
        lds[r * 66 + cc] = in ? img[y * N + x] : 0.0f;
    }
    __syncthreads();
#pragma unroll
    for (int j = 0; j < 8; ++j) {
        int r = wq * 8 + j;
        float v0 = lds[r * 66 + lane], v1 = lds[r * 66 + lane + 1];
        __half2 h = __halves2half2(__float2half(v0), __float2half(v1));
        imgPB[(size_t)(by * 64 + r) * PP + bx * 64 + lane] = *(uint32_t*)&h;
        float t0 = lds[lane * 66 + r], t1 = lds[(lane + 1) * 66 + r];
        __half2 ht = __halves2half2(__float2half(t0), __float2half(t1));
        imgTPB[(size_t)(bx * 64 + r) * PP + by * 64 + lane] = *(uint32_t*)&ht;
    }
}

// One block = (1 angle, 64 detectors, 256 i): four phases of (stage fp16-pair
// tile, sample 8 i/wave). Dynamic staged-row count trims the ~20% average
// overstage vs the 45-degree worst case. 36.9 KB x 4 blocks/CU x 512 thr =
// 100% wave occupancy. One merge + 64 atomics per block, direct into out.
__global__ __launch_bounds__(512, 8) void radon_kernel(const uint32_t* __restrict__ imgPB,
                                                       const uint32_t* __restrict__ imgTPB,
                                                       const float4* __restrict__ tab,
                                                       const int* __restrict__ flags,
                                                       float* __restrict__ out) {
    __shared__ uint32_t tile[TILE_DW];

    const int tid  = threadIdx.x;
    const int lane = tid & 63;
    const int wave = tid >> 6;           // 0..7
    const int d0 = blockIdx.x * TD;
    const int a  = blockIdx.y;
    const int i0 = blockIdx.z * TI;

    const float c = 255.5f;
    const float4 tb = tab[a];
    const float au = tb.x, bus = tb.y, av = tb.z, bvs = tb.w;

    // d-extremes of the affine offset (fixed for the whole block)
    const float xc0 = (float)d0 - c, xc1 = (float)(d0 + TD - 1) - c;
    const float buA = fmaf(bus, xc0, c), buB = fmaf(bus, xc1, c);
    const float bvA = fmaf(bvs, xc0, c), bvB = fmaf(bvs, xc1, c);
    const float buMin = fminf(buA, buB), buMax = fmaxf(buA, buB);
    const float bvMin = fminf(bvA, bvB), bvMax = fmaxf(bvA, bvB);

    // whole-block bbox (fi over all 256 i): early out if nothing can hit
    {
        const float fi0 = (float)i0 - c, fi1 = (float)(i0 + TI - 1) - c;
        const float fiLoU = (au >= 0.0f) ? fi0 : fi1, fiHiU = (au >= 0.0f) ? fi1 : fi0;
        const float fiLoV = (av >= 0.0f) ? fi0 : fi1, fiHiV = (av >= 0.0f) ? fi1 : fi0;
        if (fmaf(au, fiLoU, buMin) > (float)N || fmaf(au, fiHiU, buMax) < -1.0f ||
            fmaf(av, fiLoV, bvMin) > (float)N || fmaf(av, fiHiV, bvMax) < -1.0f)
            return;
    }

    const uint32_t* __restrict__ src = flags[a] ? imgTPB : imgPB;

    // per-lane affine offsets (shared by all phases)
    const float xcl = (float)(d0 + lane) - c;
    const float buLb = fmaf(bus, xcl, c);
    const float bvLb = fmaf(bvs, xcl, c);

    // incremental staging address bases (per lane, shared by all phases)
    const int t0g  = wave * 256 + (lane << 2);   // dword index into tile
    const int q0   = t0g / TW;
    const int c0   = t0g - q0 * TW;
    const int goff0 = q0 * PP + c0;              // dword offset from gbase

    float s = 0.0f;
#pragma unroll
    for (int ph = 0; ph < 4; ++ph) {
        const int ip = i0 + ph * 64;
        const float fi0 = (float)ip - c, fi1 = (float)(ip + 63) - c;
        const float fiLoU = (au >= 0.0f) ? fi0 : fi1, fiHiU = (au >= 0.0f) ? fi1 : fi0;
        const float fiLoV = (av >= 0.0f) ? fi0 : fi1, fiHiV = (av >= 0.0f) ? fi1 : fi0;
        const float umin = fmaf(au, fiLoU, buMin), umax = fmaf(au, fiHiU, buMax);
        const float vmin = fmaf(av, fiLoV, bvMin), vmax = fmaf(av, fiHiV, bvMax);
        const bool live = !(umin > (float)N || umax < -1.0f ||
                            vmin > (float)N || vmax < -1.0f);

        // >=1-texel margins; for live phases umin >= -90.3 so cols/rows stay
        // inside the 96-apron (no OOB).
        const int ub0 = (((int)floorf(umin)) - 1) & ~3;
        const int vb  = ((int)floorf(vmin)) - 1;
        // rows touched: vb .. floor(vmax)+2  (bottom ulp margin)
        const int rows = ((int)floorf(vmax)) + 3 - vb;       // <= 94
        const int nch  = (rows * TW + 255) >> 8;             // <= 36, block-uniform

        __syncthreads();                 // WAR: prev phase sampling complete
        if (live) {
            const uint32_t* gb = src + (vb + POFF) * PP + (ub0 + POFF) + goff0;
            int cc = c0;
#pragma unroll
            for (int st = 0; st < 5; ++st) {
                int chunk = st * 8 + wave;        // 0..39
                if (chunk < nch) load16_to_lds(gb, &tile[chunk * 256]);
                // advance by 2048 tile-dwords = 21 rows + 32 cols (mod 96)
                cc += 32;
                int wrap = (cc >= TW);
                cc = wrap ? cc - TW : cc;
                gb += 21 * PP + 32 + (wrap ? (PP - TW) : 0);
            }
        }
        __syncthreads();                 // RAW: staging visible
        if (live) {
            const float buL = buLb - (float)ub0;   // tile-local fold
            const float bvL = bvLb - (float)vb;
            const float fiw = (float)(ip + wave * 8) - c;
            float u = fmaf(au, fiw, buL);
            float v = fmaf(av, fiw, bvL);
#pragma unroll
            for (int k = 0; k < 8; ++k) {
                float wx = __builtin_amdgcn_fractf(u);
                float wy = __builtin_amdgcn_fractf(v);
                int iu = (int)u, iv = (int)v;      // trunc == floor (u,v > 0)
                int ai = iv * TW + iu;
                H2U P0, P1;
                P0.u = tile[ai];
                P1.u = tile[ai + TW];              // ds_read2_b32 0/96
                hh2 wy2 = cvt_pkrtz(wy, wy);
                hh2 m   = wy2 * (P1.h - P0.h) + P0.h;   // pk f16 vertical lerp
                hh2 wv  = cvt_pkrtz(1.0f - wx, wx);
                s = __builtin_amdgcn_fdot2(wv, m, s, false);
                u += au;                           // incremental (drift < 1e-4 px)
                v += av;
            }
        }
    }

    // ---- merge 8 wave-partials; one diverged atomic per detector ----
    __syncthreads();
    float* ft = (float*)tile;
    ft[tid] = s;
    __syncthreads();
    if (tid < 64) {
        float r = ft[tid]       + ft[tid + 64]  + ft[tid + 128] + ft[tid + 192]
                + ft[tid + 256] + ft[tid + 320] + ft[tid + 384] + ft[tid + 448];
        atomicAdd(&out[(d0 + tid) * NA + a], r);
    }
}

extern "C" void kernel_launch(void* const* d_in, const int* in_sizes, int n_in,
                              void* d_out, int out_size, void* d_ws, size_t ws_size,
                              hipStream_t stream) {
    const float* img  = (const float*)d_in[0];
    const int* angles = (const int*)d_in[1];
    float* out = (float*)d_out;
    float* ws  = (float*)d_ws;

    uint32_t* imgPB  = (uint32_t*)(ws + WS_IMGPB);
    uint32_t* imgTPB = (uint32_t*)(ws + WS_IMGTPB);
    float4*   tab    = (float4*)(ws + WS_TAB);
    int*      flags  = (int*)(ws + WS_FLAGS);

    dim3 pgrid(11, 11);
    pad_kernel<<<pgrid, 512, 0, stream>>>(img, angles, imgPB, imgTPB, tab, flags, out);

    dim3 grid(N / TD, NA, N / TI);
    radon_kernel<<<grid, 512, 0, stream>>>(imgPB, imgTPB, tab, flags, out);
}

// Round 12
// 91.019 us; speedup vs baseline: 1.1350x; 1.0192x over previous
//
#include <hip/hip_runtime.h>
#include <hip/hip_fp16.h>
#include <stdint.h>

#define N 512
#define NA 180
#define TD 64           // detectors per block
#define TI 512          // i-values per block (8 phases of 64) -> 1 block per (d-tile, a)
#define TW 96           // LDS tile pitch in pair-dwords
#define TILE_DW (36 * 256)          // 9216 dw = 36864 B -> 4 blocks/CU @ 512 thr
#define PP 708          // padded pair-image pitch (dwords)
#define PR 704          // padded pair-image rows
#define POFF 96         // padded index of image row/col 0

// d_ws float-offsets
#define WS_IMGPB  0
#define WS_IMGTPB (PR * PP)                 // 498432
#define WS_TAB    (2 * PR * PP)             // 996864 (16B aligned)
#define WS_FLAGS  (WS_TAB + 4 * NA)

typedef _Float16 hh2 __attribute__((ext_vector_type(2)));
union H2U { uint32_t u; hh2 h; };

__device__ __forceinline__ hh2 cvt_pkrtz(float a, float b) {
    return __builtin_bit_cast(hh2, __builtin_amdgcn_cvt_pkrtz(a, b));
}

__device__ __forceinline__ void load16_to_lds(const uint32_t* g, uint32_t* l) {
    __builtin_amdgcn_global_load_lds(
        (const __attribute__((address_space(1))) void*)g,
        (__attribute__((address_space(3))) void*)l,
        16 /*bytes*/, 0 /*offset*/, 0 /*aux*/);
}

// Tiled pad (512 thr): block (bx,by) covers a 64x64 padded region; builds the
// padded fp16-pair image (imgPB[r][c] = (h(I[r][c]), h(I[r][c+1]))) and its
// transpose, all accesses coalesced. Also the per-angle table. (out needs no
// zeroing: radon now fully overwrites it with plain stores.)
__global__ __launch_bounds__(512) void pad_kernel(const float* __restrict__ img,
                                                  const int* __restrict__ angles,
                                                  uint32_t* __restrict__ imgPB,
                                                  uint32_t* __restrict__ imgTPB,
                                                  float4* __restrict__ tab,
                                                  int* __restrict__ flags) {
    __shared__ float lds[65 * 66];   // pitch 66
    const int tid  = threadIdx.x;
    const int lane = tid & 63;
    const int wq   = tid >> 6;       // 0..7
    const int bx = blockIdx.x, by = blockIdx.y;
    const int b  = by * 11 + bx;

    if (b == 120 && tid < NA) {
        float t = (float)angles[tid] * 0.017453292519943295f;
        float si = sinf(t), co = cosf(t);
        int useT = fabsf(si) > fabsf(co);
        float4 e;
        if (useT) { e.x = co; e.y = -si; e.z = si; e.w = co; }
        else      { e.x = si; e.y = co;  e.z = co; e.w = -si; }
        tab[tid] = e;                // (au, bus, av, bvs)
        flags[tid] = useT;
    }

    // stage 65x65 of the padded image: padded coords (by*64+r, bx*64+c)
    for (int idx = tid; idx < 65 * 65; idx += 512) {
        int r = idx / 65, cc = idx - r * 65;
        int y = by * 64 + r - POFF, x = bx * 64 + cc - POFF;
        bool in = ((unsigned)y < N) && ((unsigned)x < N);
        lds[r * 66 + cc] = in ? img[y * N + x] : 0.0f;
    }
    __syncthreads();
#pragma unroll
    for (int j = 0; j < 8; ++j) {
        int r = wq * 8 + j;
        float v0 = lds[r * 66 + lane], v1 = lds[r * 66 + lane + 1];
        __half2 h = __halves2half2(__float2half(v0), __float2half(v1));
        imgPB[(size_t)(by * 64 + r) * PP + bx * 64 + lane] = *(uint32_t*)&h;
        float t0 = lds[lane * 66 + r], t1 = lds[(lane + 1) * 66 + r];
        __half2 ht = __halves2half2(__float2half(t0), __float2half(t1));
        imgTPB[(size_t)(bx * 64 + r) * PP + by * 64 + lane] = *(uint32_t*)&ht;
    }
}

// One block = (1 angle, 64 detectors, ALL 512 i): eight phases of (stage
// fp16-pair tile, sample 8 i/wave). Dynamic staged-row count trims the
// average overstage. 36.9 KB x 4 blocks/CU x 512 thr = 100% wave occupancy.
// Each (d,a) is owned by exactly one block -> plain stores, no atomics.
__global__ __launch_bounds__(512, 8) void radon_kernel(const uint32_t* __restrict__ imgPB,
                                                       const uint32_t* __restrict__ imgTPB,
                                                       const float4* __restrict__ tab,
                                                       const int* __restrict__ flags,
                                                       float* __restrict__ out) {
    __shared__ uint32_t tile[TILE_DW];

    const int tid  = threadIdx.x;
    const int lane = tid & 63;
    const int wave = tid >> 6;           // 0..7
    const int d0 = blockIdx.x * TD;
    const int a  = blockIdx.y;

    const float c = 255.5f;
    const float4 tb = tab[a];
    const float au = tb.x, bus = tb.y, av = tb.z, bvs = tb.w;

    // d-extremes of the affine offset (fixed for the whole block)
    const float xc0 = (float)d0 - c, xc1 = (float)(d0 + TD - 1) - c;
    const float buA = fmaf(bus, xc0, c), buB = fmaf(bus, xc1, c);
    const float bvA = fmaf(bvs, xc0, c), bvB = fmaf(bvs, xc1, c);
    const float buMin = fminf(buA, buB), buMax = fmaxf(buA, buB);
    const float bvMin = fminf(bvA, bvB), bvMax = fmaxf(bvA, bvB);

    const uint32_t* __restrict__ src = flags[a] ? imgTPB : imgPB;

    // per-lane affine offsets (shared by all phases)
    const float xcl = (float)(d0 + lane) - c;
    const float buLb = fmaf(bus, xcl, c);
    const float bvLb = fmaf(bvs, xcl, c);

    // incremental staging address bases (per lane, shared by all phases)
    const int t0g  = wave * 256 + (lane << 2);   // dword index into tile
    const int q0   = t0g / TW;
    const int c0   = t0g - q0 * TW;
    const int goff0 = q0 * PP + c0;              // dword offset from gbase

    float s = 0.0f;
    for (int ph = 0; ph < 8; ++ph) {
        const int ip = ph * 64;
        const float fi0 = (float)ip - c, fi1 = (float)(ip + 63) - c;
        const float fiLoU = (au >= 0.0f) ? fi0 : fi1, fiHiU = (au >= 0.0f) ? fi1 : fi0;
        const float fiLoV = (av >= 0.0f) ? fi0 : fi1, fiHiV = (av >= 0.0f) ? fi1 : fi0;
        const float umin = fmaf(au, fiLoU, buMin), umax = fmaf(au, fiHiU, buMax);
        const float vmin = fmaf(av, fiLoV, bvMin), vmax = fmaf(av, fiHiV, bvMax);
        const bool live = !(umin > (float)N || umax < -1.0f ||
                            vmin > (float)N || vmax < -1.0f);

        // >=1-texel margins; for live phases umin >= -90.3 so cols/rows stay
        // inside the 96-apron (no OOB).
        const int ub0 = (((int)floorf(umin)) - 1) & ~3;
        const int vb  = ((int)floorf(vmin)) - 1;
        // rows touched: vb .. floor(vmax)+2  (bottom ulp margin)
        const int rows = ((int)floorf(vmax)) + 3 - vb;       // <= 94
        const int nch  = (rows * TW + 255) >> 8;             // <= 36, block-uniform

        __syncthreads();                 // WAR: prev phase sampling complete
        if (live) {
            const uint32_t* gb = src + (vb + POFF) * PP + (ub0 + POFF) + goff0;
            int cc = c0;
#pragma unroll
            for (int st = 0; st < 5; ++st) {
                int chunk = st * 8 + wave;        // 0..39
                if (chunk < nch) load16_to_lds(gb, &tile[chunk * 256]);
                // advance by 2048 tile-dwords = 21 rows + 32 cols (mod 96)
                cc += 32;
                int wrap = (cc >= TW);
                cc = wrap ? cc - TW : cc;
                gb += 21 * PP + 32 + (wrap ? (PP - TW) : 0);
            }
        }
        __syncthreads();                 // RAW: staging visible
        if (live) {
            const float buL = buLb - (float)ub0;   // tile-local fold
            const float bvL = bvLb - (float)vb;
            const float fiw = (float)(ip + wave * 8) - c;
            float u = fmaf(au, fiw, buL);
            float v = fmaf(av, fiw, bvL);
#pragma unroll
            for (int k = 0; k < 8; ++k) {
                float wx = __builtin_amdgcn_fractf(u);
                float wy = __builtin_amdgcn_fractf(v);
                int iu = (int)u, iv = (int)v;      // trunc == floor (u,v > 0)
                int ai = iv * TW + iu;
                H2U P0, P1;
                P0.u = tile[ai];
                P1.u = tile[ai + TW];              // ds_read2_b32 0/96
                hh2 wy2 = cvt_pkrtz(wy, wy);
                hh2 m   = wy2 * (P1.h - P0.h) + P0.h;   // pk f16 vertical lerp
                hh2 wv  = cvt_pkrtz(1.0f - wx, wx);
                s = __builtin_amdgcn_fdot2(wv, m, s, false);
                u += au;                           // incremental (drift < 1e-4 px)
                v += av;
            }
        }
    }

    // ---- merge 8 wave-partials; plain store (sole owner of (d,a)) ----
    __syncthreads();
    float* ft = (float*)tile;
    ft[tid] = s;
    __syncthreads();
    if (tid < 64) {
        float r = ft[tid]       + ft[tid + 64]  + ft[tid + 128] + ft[tid + 192]
                + ft[tid + 256] + ft[tid + 320] + ft[tid + 384] + ft[tid + 448];
        out[(d0 + tid) * NA + a] = r;
    }
}

extern "C" void kernel_launch(void* const* d_in, const int* in_sizes, int n_in,
                              void* d_out, int out_size, void* d_ws, size_t ws_size,
                              hipStream_t stream) {
    const float* img  = (const float*)d_in[0];
    const int* angles = (const int*)d_in[1];
    float* out = (float*)d_out;
    float* ws  = (float*)d_ws;

    uint32_t* imgPB  = (uint32_t*)(ws + WS_IMGPB);
    uint32_t* imgTPB = (uint32_t*)(ws + WS_IMGTPB);
    float4*   tab    = (float4*)(ws + WS_TAB);
    int*      flags  = (int*)(ws + WS_FLAGS);

    dim3 pgrid(11, 11);
    pad_kernel<<<pgrid, 512, 0, stream>>>(img, angles, imgPB, imgTPB, tab, flags);

    dim3 grid(N / TD, NA);
    radon_kernel<<<grid, 512, 0, stream>>>(imgPB, imgTPB, tab, flags, out);
}

// Round 13
// 90.935 us; speedup vs baseline: 1.1361x; 1.0009x over previous
//
#include <hip/hip_runtime.h>
#include <hip/hip_fp16.h>
#include <stdint.h>

#define N 512
#define NA 180
#define TD 64           // detectors per block
#define TI 512          // i-values per block (8 phases of 64) -> 1 block per (d-tile, a)
#define TW 96           // LDS tile pitch in pair-dwords
#define TILE_DW (36 * 256)          // 9216 dw = 36864 B -> 4 blocks/CU @ 512 thr
#define PP 708          // padded pair-image pitch (dwords)
#define PR 704          // padded pair-image rows
#define POFF 96         // padded index of image row/col 0

// d_ws float-offsets
#define WS_IMGPB  0
#define WS_IMGTPB (PR * PP)                 // 498432
#define WS_TAB    (2 * PR * PP)             // 996864 (16B aligned)
#define WS_FLAGS  (WS_TAB + 4 * NA)

typedef _Float16 hh2 __attribute__((ext_vector_type(2)));
union H2U { uint32_t u; hh2 h; };

__device__ __forceinline__ hh2 cvt_pkrtz(float a, float b) {
    return __builtin_bit_cast(hh2, __builtin_amdgcn_cvt_pkrtz(a, b));
}

__device__ __forceinline__ void load16_to_lds(const uint32_t* g, uint32_t* l) {
    __builtin_amdgcn_global_load_lds(
        (const __attribute__((address_space(1))) void*)g,
        (__attribute__((address_space(3))) void*)l,
        16 /*bytes*/, 0 /*offset*/, 0 /*aux*/);
}

// Tiled pad (512 thr): block (bx,by) covers a 64x64 padded region; builds the
// padded fp16-pair image (imgPB[r][c] = (h(I[r][c]), h(I[r][c+1]))) and its
// transpose, all accesses coalesced. Also the per-angle table. (out needs no
// zeroing: radon fully overwrites it with plain stores.)
__global__ __launch_bounds__(512) void pad_kernel(const float* __restrict__ img,
                                                  const int* __restrict__ angles,
                                                  uint32_t* __restrict__ imgPB,
                                                  uint32_t* __restrict__ imgTPB,
                                                  float4* __restrict__ tab,
                                                  int* __restrict__ flags) {
    __shared__ float lds[65 * 66];   // pitch 66
    const int tid  = threadIdx.x;
    const int lane = tid & 63;
    const int wq   = tid >> 6;       // 0..7
    const int bx = blockIdx.x, by = blockIdx.y;
    const int b  = by * 11 + bx;

    if (b == 120 && tid < NA) {
        float t = (float)angles[tid] * 0.017453292519943295f;
        float si = sinf(t), co = cosf(t);
        int useT = fabsf(si) > fabsf(co);
        float4 e;
        if (useT) { e.x = co; e.y = -si; e.z = si; e.w = co; }
        else      { e.x = si; e.y = co;  e.z = co; e.w = -si; }
        tab[tid] = e;                // (au, bus, av, bvs)
        flags[tid] = useT;
    }

    // stage 65x65 of the padded image: padded coords (by*64+r, bx*64+c)
    for (int idx = tid; idx < 65 * 65; idx += 512) {
        int r = idx / 65, cc = idx - r * 65;
        int y = by * 64 + r - POFF, x = bx * 64 + cc - POFF;
        bool in = ((unsigned)y < N) && ((unsigned)x < N);
        lds[r * 66 + cc] = in ? img[y * N + x] : 0.0f;
    }
    __syncthreads();
#pragma unroll
    for (int j = 0; j < 8; ++j) {
        int r = wq * 8 + j;
        float v0 = lds[r * 66 + lane], v1 = lds[r * 66 + lane + 1];
        __half2 h = __halves2half2(__float2half(v0), __float2half(v1));
        imgPB[(size_t)(by * 64 + r) * PP + bx * 64 + lane] = *(uint32_t*)&h;
        float t0 = lds[lane * 66 + r], t1 = lds[(lane + 1) * 66 + r];
        __half2 ht = __halves2half2(__float2half(t0), __float2half(t1));
        imgTPB[(size_t)(bx * 64 + r) * PP + by * 64 + lane] = *(uint32_t*)&ht;
    }
}

// One block = (1 angle, 64 detectors, ALL 512 i): eight phases of (stage
// fp16-pair tile, sample 8 i/wave). Phase ORDER is rotated per block so the
// 4 co-resident blocks on a CU don't hit their staging drains in lockstep;
// dead phases (block-uniform) skip their barriers entirely.
__global__ __launch_bounds__(512, 8) void radon_kernel(const uint32_t* __restrict__ imgPB,
                                                       const uint32_t* __restrict__ imgTPB,
                                                       const float4* __restrict__ tab,
                                                       const int* __restrict__ flags,
                                                       float* __restrict__ out) {
    __shared__ uint32_t tile[TILE_DW];

    const int tid  = threadIdx.x;
    const int lane = tid & 63;
    const int wave = tid >> 6;           // 0..7
    const int d0 = blockIdx.x * TD;
    const int a  = blockIdx.y;
    const int rot = (blockIdx.x + blockIdx.y) & 7;   // de-phase co-resident blocks

    const float c = 255.5f;
    const float4 tb = tab[a];
    const float au = tb.x, bus = tb.y, av = tb.z, bvs = tb.w;

    // d-extremes of the affine offset (fixed for the whole block)
    const float xc0 = (float)d0 - c, xc1 = (float)(d0 + TD - 1) - c;
    const float buA = fmaf(bus, xc0, c), buB = fmaf(bus, xc1, c);
    const float bvA = fmaf(bvs, xc0, c), bvB = fmaf(bvs, xc1, c);
    const float buMin = fminf(buA, buB), buMax = fmaxf(buA, buB);
    const float bvMin = fminf(bvA, bvB), bvMax = fmaxf(bvA, bvB);

    const uint32_t* __restrict__ src = flags[a] ? imgTPB : imgPB;

    // per-lane affine offsets (shared by all phases)
    const float xcl = (float)(d0 + lane) - c;
    const float buLb = fmaf(bus, xcl, c);
    const float bvLb = fmaf(bvs, xcl, c);

    // incremental staging address bases (per lane, shared by all phases)
    const int t0g  = wave * 256 + (lane << 2);   // dword index into tile
    const int q0   = t0g / TW;
    const int c0   = t0g - q0 * TW;
    const int goff0 = q0 * PP + c0;              // dword offset from gbase

    float s = 0.0f;
    for (int p8 = 0; p8 < 8; ++p8) {
        const int ph = (p8 + rot) & 7;
        const int ip = ph * 64;
        const float fi0 = (float)ip - c, fi1 = (float)(ip + 63) - c;
        const float fiLoU = (au >= 0.0f) ? fi0 : fi1, fiHiU = (au >= 0.0f) ? fi1 : fi0;
        const float fiLoV = (av >= 0.0f) ? fi0 : fi1, fiHiV = (av >= 0.0f) ? fi1 : fi0;
        const float umin = fmaf(au, fiLoU, buMin), umax = fmaf(au, fiHiU, buMax);
        const float vmin = fmaf(av, fiLoV, bvMin), vmax = fmaf(av, fiHiV, bvMax);
        // block-uniform: skipping barriers is legal (all threads agree)
        if (umin > (float)N || umax < -1.0f || vmin > (float)N || vmax < -1.0f)
            continue;

        // >=1-texel margins; for live phases umin >= -90.3 so cols/rows stay
        // inside the 96-apron (no OOB).
        const int ub0 = (((int)floorf(umin)) - 1) & ~3;
        const int vb  = ((int)floorf(vmin)) - 1;
        // rows touched: vb .. floor(vmax)+2  (bottom ulp margin)
        const int rows = ((int)floorf(vmax)) + 3 - vb;       // <= 94
        const int nch  = (rows * TW + 255) >> 8;             // <= 36, block-uniform

        __syncthreads();                 // WAR: prev live phase sampling done
        {
            const uint32_t* gb = src + (vb + POFF) * PP + (ub0 + POFF) + goff0;
            int cc = c0;
#pragma unroll
            for (int st = 0; st < 5; ++st) {
                int chunk = st * 8 + wave;        // 0..39
                if (chunk < nch) load16_to_lds(gb, &tile[chunk * 256]);
                // advance by 2048 tile-dwords = 21 rows + 32 cols (mod 96)
                cc += 32;
                int wrap = (cc >= TW);
                cc = wrap ? cc - TW : cc;
                gb += 21 * PP + 32 + (wrap ? (PP - TW) : 0);
            }
        }
        __syncthreads();                 // RAW: staging visible
        {
            const float buL = buLb - (float)ub0;   // tile-local fold
            const float bvL = bvLb - (float)vb;
            const float fiw = (float)(ip + wave * 8) - c;
            float u = fmaf(au, fiw, buL);
            float v = fmaf(av, fiw, bvL);
#pragma unroll
            for (int k = 0; k < 8; ++k) {
                float wx = __builtin_amdgcn_fractf(u);
                float wy = __builtin_amdgcn_fractf(v);
                int iu = (int)u, iv = (int)v;      // trunc == floor (u,v > 0)
                int ai = iv * TW + iu;
                H2U P0, P1;
                P0.u = tile[ai];
                P1.u = tile[ai + TW];              // ds_read2_b32 0/96
                hh2 wy2 = cvt_pkrtz(wy, wy);
                hh2 m   = wy2 * (P1.h - P0.h) + P0.h;   // pk f16 vertical lerp
                hh2 wv  = cvt_pkrtz(1.0f - wx, wx);
                s = __builtin_amdgcn_fdot2(wv, m, s, false);
                u += au;                           // incremental (drift < 1e-4 px)
                v += av;
            }
        }
    }

    // ---- merge 8 wave-partials; plain store (sole owner of (d,a)) ----
    __syncthreads();
    float* ft = (float*)tile;
    ft[tid] = s;
    __syncthreads();
    if (tid < 64) {
        float r = ft[tid]       + ft[tid + 64]  + ft[tid + 128] + ft[tid + 192]
                + ft[tid + 256] + ft[tid + 320] + ft[tid + 384] + ft[tid + 448];
        out[(d0 + tid) * NA + a] = r;
    }
}

extern "C" void kernel_launch(void* const* d_in, const int* in_sizes, int n_in,
                              void* d_out, int out_size, void* d_ws, size_t ws_size,
                              hipStream_t stream) {
    const float* img  = (const float*)d_in[0];
    const int* angles = (const int*)d_in[1];
    float* out = (float*)d_out;
    float* ws  = (float*)d_ws;

    uint32_t* imgPB  = (uint32_t*)(ws + WS_IMGPB);
    uint32_t* imgTPB = (uint32_t*)(ws + WS_IMGTPB);
    float4*   tab    = (float4*)(ws + WS_TAB);
    int*      flags  = (int*)(ws + WS_FLAGS);

    dim3 pgrid(11, 11);
    pad_kernel<<<pgrid, 512, 0, stream>>>(img, angles, imgPB, imgTPB, tab, flags);

    dim3 grid(N / TD, NA);
    radon_kernel<<<grid, 512, 0, stream>>>(imgPB, imgTPB, tab, flags, out);
}